// Round 13
// baseline (2306.766 us; speedup 1.0000x reference)
//
#include <hip/hip_runtime.h>
#include <hip/hip_bf16.h>
#include <stdint.h>

// Problem constants (fixed by the reference)
#define N_NODES 100000
#define N_EDGES 400000
#define N_GRAPH 4096
#define DIMD    300
#define NLAYER  5
// padded dims
#define HPAD   304   // h row stride (bf16), 38 x 8
#define KP1    320   // aggb row stride = K of GEMM1 (5 x 64)
#define W1ROWS 640   // w1b rows (5 chunks of 128); also k-stride of w2b
#define WID2   320   // w2b rows (20 n-frags of 16)
#define MROWS  64    // node rows per k_mlp block
#define HGR    64    // graphs per head block

typedef __attribute__((ext_vector_type(8))) short bf16x8_t;
typedef __attribute__((ext_vector_type(4))) float f32x4_t;

__device__ __forceinline__ void gload_lds16(const void* g, void* l) {
  auto gp = (__attribute__((address_space(1))) void*)(uintptr_t)g;
  auto lp = (__attribute__((address_space(3))) void*)(uint32_t)(uintptr_t)l;
  __builtin_amdgcn_global_load_lds(gp, lp, 16, 0, 0);
}
__device__ __forceinline__ short f2bs(float f) {
  __hip_bfloat16 b = __float2bfloat16(f); return *(short*)&b;
}
__device__ __forceinline__ float bs2f(short s) {
  __hip_bfloat16 b; *(short*)&b = s; return __bfloat162float(b);
}

// ---------------- CSR build ----------------
__global__ void k_hist(const int* __restrict__ ei, int* __restrict__ cur) {
  const int e = blockIdx.x * blockDim.x + threadIdx.x;
  if (e < N_EDGES) atomicAdd(&cur[ei[N_EDGES + e]], 1);
}

__global__ void k_scan1(int* __restrict__ cur, int* __restrict__ off, int* __restrict__ bsum) {
  __shared__ int buf[1024];
  const int tid = threadIdx.x;
  const int i = blockIdx.x * 1024 + tid;
  int v = (i < N_NODES) ? cur[i] : 0;
  buf[tid] = v;
  __syncthreads();
  for (int s = 1; s < 1024; s <<= 1) {
    int t = (tid >= s) ? buf[tid - s] : 0;
    __syncthreads();
    buf[tid] += t;
    __syncthreads();
  }
  if (i < N_NODES) { off[i + 1] = buf[tid]; cur[i] = 0; }
  if (tid == 1023) bsum[blockIdx.x] = buf[1023];
}

__global__ void k_scan2(int* __restrict__ bsum, int nb) {
  if (threadIdx.x == 0 && blockIdx.x == 0) {
    int run = 0;
    for (int b = 0; b < nb; ++b) { int v = bsum[b]; bsum[b] = run; run += v; }
  }
}

__global__ void k_scan3(int* __restrict__ off, const int* __restrict__ bsum) {
  const int i = blockIdx.x * blockDim.x + threadIdx.x;
  if (i == 0) off[0] = 0;
  if (i < N_NODES) off[i + 1] += bsum[i >> 10];
}

__global__ void k_fill(const int* __restrict__ ei, const int* __restrict__ ea,
                       const int* __restrict__ off, int* __restrict__ cur,
                       int* __restrict__ csr) {
  const int e = blockIdx.x * blockDim.x + threadIdx.x;
  if (e < N_EDGES) {
    const int d = ei[N_EDGES + e];
    const int pos = atomicAdd(&cur[d], 1);
    const int c = ea[2 * e] * 3 + ea[2 * e + 1];   // attr values in [0,3)
    csr[off[d] + pos] = (ei[e] << 4) | c;          // src<<4 | comb-index
  }
}

// ---------------- small precompute ----------------
// comb[l][r][0..HPAD): r<9 -> ee1[l][r/3]+ee2[l][r%3]; r==9 -> self-loop; pad cols 0
__global__ void k_comb(const float* __restrict__ e1, const float* __restrict__ e2,
                       float* __restrict__ comb) {
  const int idx = blockIdx.x * blockDim.x + threadIdx.x;
  if (idx >= NLAYER * 10 * HPAD) return;
  const int l = idx / (10 * HPAD);
  const int r = (idx / HPAD) % 10;
  const int d = idx % HPAD;
  float v = 0.f;
  if (d < DIMD) {
    int a, b;
    if (r < 9) { a = r / 3; b = r % 3; } else { a = 4; b = 0; }
    v = e1[(l * 6 + a) * DIMD + d] + e2[(l * 3 + b) * DIMD + d];
  }
  comb[idx] = v;
}

// w1 (L,300,600) f32 -> w1b (L,[640 n][320 k]) bf16, zero-padded
__global__ void k_wc1(const float* __restrict__ w, __hip_bfloat16* __restrict__ wb) {
  const int idx = blockIdx.x * blockDim.x + threadIdx.x;
  if (idx >= NLAYER * W1ROWS * KP1) return;
  const int l = idx / (W1ROWS * KP1);
  const int n = (idx / KP1) % W1ROWS;
  const int k = idx % KP1;
  float v = 0.f;
  if (n < 600 && k < DIMD) v = w[((long)l * DIMD + k) * 600 + n];
  wb[idx] = __float2bfloat16(v);
}

// w2 (L,600,300) f32 -> w2b (L,[320 n][640 k]) bf16, zero-padded
__global__ void k_wc2(const float* __restrict__ w, __hip_bfloat16* __restrict__ wb) {
  const int idx = blockIdx.x * blockDim.x + threadIdx.x;
  if (idx >= NLAYER * WID2 * W1ROWS) return;
  const int l = idx / (WID2 * W1ROWS);
  const int n = (idx / W1ROWS) % WID2;
  const int k = idx % W1ROWS;
  float v = 0.f;
  if (n < DIMD && k < 600) v = w[((long)l * 600 + k) * DIMD + n];
  wb[idx] = __float2bfloat16(v);
}

// head w1 (300,512) f32 -> hw1b [512 n][320 k] bf16, zero-padded
__global__ void k_wch(const float* __restrict__ w, __hip_bfloat16* __restrict__ wb) {
  const int idx = blockIdx.x * blockDim.x + threadIdx.x;
  if (idx >= 512 * KP1) return;
  const int n = idx / KP1;
  const int k = idx % KP1;
  float v = (k < DIMD) ? w[(long)k * 512 + n] : 0.f;
  wb[idx] = __float2bfloat16(v);
}

// node input embedding -> bf16 h (one 16B chunk per thread)
__global__ void k_nemb(const int* __restrict__ x, const float* __restrict__ ae1,
                       const float* __restrict__ ae2, __hip_bfloat16* __restrict__ h) {
  const int gid = blockIdx.x * blockDim.x + threadIdx.x;
  if (gid >= N_NODES * 38) return;
  const int node = gid / 38;
  const int l = gid % 38;
  bf16x8_t ov;
#pragma unroll
  for (int j = 0; j < 8; ++j) ov[j] = 0;
  {
    const int i0 = x[2 * node], i1 = x[2 * node + 1];
    const float* r1 = ae1 + (long)i0 * DIMD + l * 8;
    const float* r2 = ae2 + (long)i1 * DIMD + l * 8;
#pragma unroll
    for (int j = 0; j < 8; ++j) {
      const int d = l * 8 + j;
      if (d < DIMD) ov[j] = f2bs(r1[j] + r2[j]);
    }
  }
  *(bf16x8_t*)(h + (long)node * HPAD + l * 8) = ov;
}

// ---------------- aggregation: one wave/node, 2x-unrolled edge gathers ----------------
__global__ __launch_bounds__(256)
void k_agg(const __hip_bfloat16* __restrict__ h, __hip_bfloat16* __restrict__ aggb,
           const int* __restrict__ csr, const int* __restrict__ off,
           const float* __restrict__ comb) {
  const int wv = threadIdx.x >> 6;
  const int lane = threadIdx.x & 63;
  const int node = blockIdx.x * 4 + wv;
  if (node >= N_NODES) return;
  if (lane >= 40) return;                 // 40 lanes cover KP1=320 output cols
  const bool act = lane < 38;             // 38 lanes cover HPAD=304 input cols
  float acc[8];
  if (act) {
    const bf16x8_t hv = *(const bf16x8_t*)(h + (long)node * HPAD + lane * 8);
    const float* c9 = comb + 9 * HPAD + lane * 8;
#pragma unroll
    for (int j = 0; j < 8; ++j) acc[j] = bs2f(hv[j]) + c9[j];  // h + self_emb
  } else {
#pragma unroll
    for (int j = 0; j < 8; ++j) acc[j] = 0.f;
  }
  const int p0 = off[node], p1 = off[node + 1];
  int p = p0;
  for (; p + 1 < p1; p += 2) {
    const int v0 = csr[p], v1 = csr[p + 1];
    if (act) {
      const bf16x8_t h0 = *(const bf16x8_t*)(h + (long)(v0 >> 4) * HPAD + lane * 8);
      const bf16x8_t h1 = *(const bf16x8_t*)(h + (long)(v1 >> 4) * HPAD + lane * 8);
      const float* c0 = comb + (v0 & 15) * HPAD + lane * 8;
      const float* c1 = comb + (v1 & 15) * HPAD + lane * 8;
#pragma unroll
      for (int j = 0; j < 8; ++j) acc[j] += bs2f(h0[j]) + c0[j];
#pragma unroll
      for (int j = 0; j < 8; ++j) acc[j] += bs2f(h1[j]) + c1[j];
    }
  }
  if (p < p1) {
    const int v0 = csr[p];
    if (act) {
      const bf16x8_t h0 = *(const bf16x8_t*)(h + (long)(v0 >> 4) * HPAD + lane * 8);
      const float* c0 = comb + (v0 & 15) * HPAD + lane * 8;
#pragma unroll
      for (int j = 0; j < 8; ++j) acc[j] += bs2f(h0[j]) + c0[j];
    }
  }
  bf16x8_t ov;
#pragma unroll
  for (int j = 0; j < 8; ++j) ov[j] = act ? f2bs(acc[j]) : (short)0;
  *(bf16x8_t*)(aggb + (long)node * KP1 + lane * 8) = ov;   // cols 304..319 = 0
}

// ---------------- fused MLP: 64-row tile, 8 waves (2 row x 4 col), no VGPR pin ----------------
// R8 geometry with the launch-bound bug removed: 512 threads, accB[2][5]=40 VGPR/wave,
// A staged once in LDS (40 KB, swizzled); P double-buffered (2 x 16 KB);
// region per chunk = phaseB(c) || phaseA(c+1), ONE barrier per chunk.
// LDS 72 KB -> 2 blocks/CU = 16 waves/CU = 4 waves/SIMD (vs R5's 2/SIMD at m-frag=4).
__global__ __launch_bounds__(512)
void k_mlp(const __hip_bfloat16* __restrict__ aggb,
           const __hip_bfloat16* __restrict__ w1b,   // [640][320]
           const __hip_bfloat16* __restrict__ w2b,   // [320][640]
           const float* __restrict__ b1,             // [600]
           const float* __restrict__ b2,             // [300]
           const float* __restrict__ bng, const float* __restrict__ bnb,
           const float* __restrict__ bnm, const float* __restrict__ bnv,
           int reluFlag,
           __hip_bfloat16* __restrict__ h) {
  __shared__ __align__(16) char As[MROWS * 640];    // 40 KB, swizzled
  __shared__ __align__(16) char P[2 * MROWS * 256]; // 2 x 16 KB, swizzled
  const int tid = threadIdx.x;
  const int lane = tid & 63;
  const int wv = tid >> 6;         // 0..7
  const int wr = wv >> 2;          // 0..1 row group (32 rows)
  const int wc = wv & 3;           // 0..3 col group
  const int fr = lane & 15;
  const int kg = lane >> 4;        // 0..3
  const int row0 = blockIdx.x * MROWS;

  // ---- stage A-tile once: LDS granule (r,gin) <- global granule (gin ^ (r&7)) ----
#pragma unroll
  for (int it = 0; it < 5; ++it) {
    const int g = it * 512 + tid;          // 64 rows x 40 granules
    const int r = g / 40;
    const int gin = g - r * 40;
    int ar = row0 + r;
    if (ar >= N_NODES) ar = N_NODES - 1;   // clamp; stores are guarded
    gload_lds16((const char*)aggb + (size_t)ar * 640 + (size_t)((gin ^ (r & 7)) * 16),
                As + g * 16);
  }

  f32x4_t accB[2][5];
#pragma unroll
  for (int m = 0; m < 2; ++m)
#pragma unroll
    for (int n = 0; n < 5; ++n) accB[m][n] = (f32x4_t){0.f, 0.f, 0.f, 0.f};

  __syncthreads();   // A staged

  // ---- phase A(0) -> P[0] ----
  {
    f32x4_t accA[2][2];
#pragma unroll
    for (int m = 0; m < 2; ++m)
#pragma unroll
      for (int n = 0; n < 2; ++n) accA[m][n] = (f32x4_t){0.f, 0.f, 0.f, 0.f};
    const __hip_bfloat16* w1c = w1b + (size_t)(wc * 32) * KP1;
#pragma unroll
    for (int ks = 0; ks < 10; ++ks) {
      const int k2 = ks * 64 + kg * 16;
      bf16x8_t af[2], bfr[2];
#pragma unroll
      for (int m = 0; m < 2; ++m) {
        const int r = wr * 32 + m * 16 + fr;
        af[m] = *(const bf16x8_t*)(As + r * 640 + (k2 ^ ((r & 7) << 4)));
      }
#pragma unroll
      for (int n = 0; n < 2; ++n)
        bfr[n] = *(const bf16x8_t*)(w1c + (size_t)(n * 16 + fr) * KP1 + ks * 32 + kg * 8);
#pragma unroll
      for (int m = 0; m < 2; ++m)
#pragma unroll
        for (int n = 0; n < 2; ++n)
          accA[m][n] = __builtin_amdgcn_mfma_f32_16x16x32_bf16(af[m], bfr[n], accA[m][n], 0, 0, 0);
    }
#pragma unroll
    for (int n = 0; n < 2; ++n) {
      const int col = wc * 32 + n * 16 + fr;
      const float bv = (col < 600) ? b1[col] : 0.f;
#pragma unroll
      for (int m = 0; m < 2; ++m)
#pragma unroll
        for (int j = 0; j < 4; ++j) {
          const int prow = wr * 32 + m * 16 + kg * 4 + j;
          const int pcol = wc * 32 + n * 16 + fr;
          *(short*)(P + prow * 256 + ((pcol * 2) ^ ((prow & 7) << 4))) =
              f2bs(fmaxf(accA[m][n][j] + bv, 0.f));
        }
    }
  }
  __syncthreads();   // P[0] ready

  // ---- chunk regions: phaseB(c) from P[c&1]  ||  phaseA(c+1) -> P[(c+1)&1] ----
#pragma unroll
  for (int c = 0; c < 5; ++c) {
    const char* Pc = P + (c & 1) * (MROWS * 256);
    char* Pn = P + ((c + 1) & 1) * (MROWS * 256);

    // phase B(c): accB += P(rows of this row-group x 128) @ w2chunk(128x320)
#pragma unroll
    for (int ks = 0; ks < 4; ++ks) {
      bf16x8_t af2[2], bf2[5];
#pragma unroll
      for (int m = 0; m < 2; ++m) {
        const int pr = wr * 32 + m * 16 + fr;
        af2[m] = *(const bf16x8_t*)(Pc + pr * 256 + ((ks * 64 + kg * 16) ^ ((pr & 7) << 4)));
      }
      const int k2 = c * 128 + ks * 32 + kg * 8;
#pragma unroll
      for (int n = 0; n < 5; ++n)
        bf2[n] = *(const bf16x8_t*)(w2b + (size_t)(wc * 80 + n * 16 + fr) * W1ROWS + k2);
#pragma unroll
      for (int m = 0; m < 2; ++m)
#pragma unroll
        for (int n = 0; n < 5; ++n)
          accB[m][n] = __builtin_amdgcn_mfma_f32_16x16x32_bf16(af2[m], bf2[n], accB[m][n], 0, 0, 0);
    }

    // phase A(c+1) -> P[(c+1)&1]
    if (c < 4) {
      f32x4_t accA[2][2];
#pragma unroll
      for (int m = 0; m < 2; ++m)
#pragma unroll
        for (int n = 0; n < 2; ++n) accA[m][n] = (f32x4_t){0.f, 0.f, 0.f, 0.f};
      const __hip_bfloat16* w1c = w1b + (size_t)((c + 1) * 128 + wc * 32) * KP1;
#pragma unroll
      for (int ks = 0; ks < 10; ++ks) {
        const int k2 = ks * 64 + kg * 16;
        bf16x8_t af[2], bfr[2];
#pragma unroll
        for (int m = 0; m < 2; ++m) {
          const int r = wr * 32 + m * 16 + fr;
          af[m] = *(const bf16x8_t*)(As + r * 640 + (k2 ^ ((r & 7) << 4)));
        }
#pragma unroll
        for (int n = 0; n < 2; ++n)
          bfr[n] = *(const bf16x8_t*)(w1c + (size_t)(n * 16 + fr) * KP1 + ks * 32 + kg * 8);
#pragma unroll
        for (int m = 0; m < 2; ++m)
#pragma unroll
          for (int n = 0; n < 2; ++n)
            accA[m][n] = __builtin_amdgcn_mfma_f32_16x16x32_bf16(af[m], bfr[n], accA[m][n], 0, 0, 0);
      }
#pragma unroll
      for (int n = 0; n < 2; ++n) {
        const int col = (c + 1) * 128 + wc * 32 + n * 16 + fr;
        const float bv = (col < 600) ? b1[col] : 0.f;
#pragma unroll
        for (int m = 0; m < 2; ++m)
#pragma unroll
          for (int j = 0; j < 4; ++j) {
            const int prow = wr * 32 + m * 16 + kg * 4 + j;
            const int pcol = wc * 32 + n * 16 + fr;
            *(short*)(Pn + prow * 256 + ((pcol * 2) ^ ((prow & 7) << 4))) =
                f2bs(fmaxf(accA[m][n][j] + bv, 0.f));
          }
      }
    }
    __syncthreads();
  }

  // ---- epilogue: h = BN(accB + b2)(+relu), bf16, col 300..303 -> 0 ----
  float scale[5], shift[5];
#pragma unroll
  for (int n = 0; n < 5; ++n) {
    const int col = wc * 80 + n * 16 + fr;
    if (col < DIMD) {
      const float sc = rsqrtf(bnv[col] + 1e-5f) * bng[col];
      scale[n] = sc;
      shift[n] = (b2[col] - bnm[col]) * sc + bnb[col];
    } else { scale[n] = 0.f; shift[n] = 0.f; }
  }
#pragma unroll
  for (int m = 0; m < 2; ++m) {
#pragma unroll
    for (int n = 0; n < 5; ++n) {
      const int col = wc * 80 + n * 16 + fr;
      if (col >= HPAD) continue;
#pragma unroll
      for (int j = 0; j < 4; ++j) {
        const int node = row0 + wr * 32 + m * 16 + kg * 4 + j;
        if (node >= N_NODES) continue;
        float v = 0.f;
        if (col < DIMD) {
          v = accB[m][n][j] * scale[n] + shift[n];
          if (reluFlag) v = fmaxf(v, 0.f);
        }
        h[(size_t)node * HPAD + col] = __float2bfloat16(v);
      }
    }
  }
}

// ---------------- pooling (batch sorted -> binary search), bf16 out ----------------
__device__ __forceinline__ int lbound(const int* a, int n, int key) {
  int lo = 0, hi = n;
  while (lo < hi) { int mid = (lo + hi) >> 1; if (a[mid] < key) lo = mid + 1; else hi = mid; }
  return lo;
}

__global__ void k_pool(const __hip_bfloat16* __restrict__ h, const int* __restrict__ batch,
                       __hip_bfloat16* __restrict__ pooled) {
  __shared__ int se[2];
  const int g = blockIdx.x;
  if (threadIdx.x < 2) se[threadIdx.x] = lbound(batch, N_NODES, g + threadIdx.x);
  __syncthreads();
  const int d = threadIdx.x;
  if (d < KP1) {
    float a = 0.f;
    if (d < DIMD)
      for (int i = se[0]; i < se[1]; ++i) a += __bfloat162float(h[(long)i * HPAD + d]);
    pooled[(long)g * KP1 + d] = __float2bfloat16(d < DIMD ? a : 0.f);
  }
}

// ---------------- MFMA head: out = relu(pooled@hw1+hb1)@hw2+hb2 ----------------
__global__ __launch_bounds__(256)
void k_head(const __hip_bfloat16* __restrict__ pooled,  // [4096][320] bf16
            const __hip_bfloat16* __restrict__ hw1b,    // [512][320] bf16
            const float* __restrict__ hb1, const float* __restrict__ hw2,
            const float* __restrict__ hb2, float* __restrict__ out) {
  __shared__ __align__(16) char As[HGR * 640];   // 40 KB
  __shared__ float sred[4][HGR][2];
  const int tid = threadIdx.x;
  const int lane = tid & 63;
  const int wc = tid >> 6;
  const int fr = lane & 15;
  const int kg = lane >> 4;
  const int g0 = blockIdx.x * HGR;

#pragma unroll
  for (int it = 0; it < 10; ++it) {
    const int g = it * 256 + tid;
    const int r = g / 40;
    const int gin = g - r * 40;
    gload_lds16((const char*)pooled + (size_t)(g0 + r) * 640 + (size_t)((gin ^ (r & 7)) * 16),
                As + g * 16);
  }

  f32x4_t acc[4][8];
#pragma unroll
  for (int m = 0; m < 4; ++m)
#pragma unroll
    for (int n = 0; n < 8; ++n) acc[m][n] = (f32x4_t){0.f, 0.f, 0.f, 0.f};

  __syncthreads();

#pragma unroll
  for (int ks = 0; ks < 10; ++ks) {
    const int k2 = ks * 64 + kg * 16;
    bf16x8_t af[4], bw[8];
#pragma unroll
    for (int m = 0; m < 4; ++m) {
      const int r = m * 16 + fr;
      af[m] = *(const bf16x8_t*)(As + r * 640 + (k2 ^ ((r & 7) << 4)));
    }
#pragma unroll
    for (int n = 0; n < 8; ++n)
      bw[n] = *(const bf16x8_t*)(hw1b + (size_t)(wc * 128 + n * 16 + fr) * KP1 + ks * 32 + kg * 8);
#pragma unroll
    for (int m = 0; m < 4; ++m)
#pragma unroll
      for (int n = 0; n < 8; ++n)
        acc[m][n] = __builtin_amdgcn_mfma_f32_16x16x32_bf16(af[m], bw[n], acc[m][n], 0, 0, 0);
  }

  float p0[4][4], p1[4][4];
#pragma unroll
  for (int m = 0; m < 4; ++m)
#pragma unroll
    for (int j = 0; j < 4; ++j) { p0[m][j] = 0.f; p1[m][j] = 0.f; }
#pragma unroll
  for (int n = 0; n < 8; ++n) {
    const int col = wc * 128 + n * 16 + fr;
    const float bv = hb1[col];
    const float wa = hw2[2 * col], wb = hw2[2 * col + 1];
#pragma unroll
    for (int m = 0; m < 4; ++m)
#pragma unroll
      for (int j = 0; j < 4; ++j) {
        const float z = fmaxf(acc[m][n][j] + bv, 0.f);
        p0[m][j] = fmaf(z, wa, p0[m][j]);
        p1[m][j] = fmaf(z, wb, p1[m][j]);
      }
  }
#pragma unroll
  for (int m = 0; m < 4; ++m)
#pragma unroll
    for (int j = 0; j < 4; ++j) {
#pragma unroll
      for (int s = 1; s < 16; s <<= 1) {
        p0[m][j] += __shfl_xor(p0[m][j], s, 64);
        p1[m][j] += __shfl_xor(p1[m][j], s, 64);
      }
    }
  if (fr == 0) {
#pragma unroll
    for (int m = 0; m < 4; ++m)
#pragma unroll
      for (int j = 0; j < 4; ++j) {
        const int row = m * 16 + kg * 4 + j;
        sred[wc][row][0] = p0[m][j];
        sred[wc][row][1] = p1[m][j];
      }
  }
  __syncthreads();
  if (tid < HGR) {
    const int row = tid;
    float a0 = sred[0][row][0] + sred[1][row][0] + sred[2][row][0] + sred[3][row][0];
    float a1 = sred[0][row][1] + sred[1][row][1] + sred[2][row][1] + sred[3][row][1];
    out[2 * (g0 + row)] = a0 + hb2[0];
    out[2 * (g0 + row) + 1] = a1 + hb2[1];
  }
}

// sentinel: signal "workspace too small" through the only visible channel
__global__ void k_sentinel(float* out) { out[threadIdx.x] = 1.0e6f; }

// ---------------- launch ----------------
extern "C" void kernel_launch(void* const* d_in, const int* in_sizes, int n_in,
                              void* d_out, int out_size, void* d_ws, size_t ws_size,
                              hipStream_t stream) {
  const int*   x     = (const int*)d_in[0];
  const int*   ei    = (const int*)d_in[1];
  const int*   ea    = (const int*)d_in[2];
  const int*   batch = (const int*)d_in[3];
  const float* ae1   = (const float*)d_in[4];
  const float* ae2   = (const float*)d_in[5];
  const float* ee1   = (const float*)d_in[6];
  const float* ee2   = (const float*)d_in[7];
  const float* w1    = (const float*)d_in[8];
  const float* b1    = (const float*)d_in[9];
  const float* w2    = (const float*)d_in[10];
  const float* b2    = (const float*)d_in[11];
  const float* bng   = (const float*)d_in[12];
  const float* bnbp  = (const float*)d_in[13];
  const float* bnm   = (const float*)d_in[14];
  const float* bnv   = (const float*)d_in[15];
  const float* hw1   = (const float*)d_in[16];
  const float* hb1   = (const float*)d_in[17];
  const float* hw2   = (const float*)d_in[18];
  const float* hb2   = (const float*)d_in[19];
  float* out = (float*)d_out;

  char* ws = (char*)d_ws;
  size_t o = 0;
  auto alloc = [&](size_t bytes) { size_t p = o; o += (bytes + 255) & ~(size_t)255; return p; };
  __hip_bfloat16* h      = (__hip_bfloat16*)(ws + alloc((size_t)N_NODES * HPAD * 2));   // 60.8 MB
  __hip_bfloat16* aggb   = (__hip_bfloat16*)(ws + alloc((size_t)N_NODES * KP1 * 2));    // 64 MB
  __hip_bfloat16* w1b    = (__hip_bfloat16*)(ws + alloc((size_t)NLAYER * W1ROWS * KP1 * 2));
  __hip_bfloat16* w2b    = (__hip_bfloat16*)(ws + alloc((size_t)NLAYER * WID2 * W1ROWS * 2));
  __hip_bfloat16* hw1b   = (__hip_bfloat16*)(ws + alloc((size_t)512 * KP1 * 2));
  float*          comb   = (float*)         (ws + alloc((size_t)NLAYER * 10 * HPAD * 4));
  int*            offp   = (int*)           (ws + alloc((size_t)(N_NODES + 1) * 4));
  int*            cur    = (int*)           (ws + alloc((size_t)N_NODES * 4));
  int*            csr    = (int*)           (ws + alloc((size_t)N_EDGES * 4));
  __hip_bfloat16* pooled = (__hip_bfloat16*)(ws + alloc((size_t)N_GRAPH * KP1 * 2));
  int*            bsum   = (int*)           (ws + alloc(128 * 4));
  if (o > ws_size) {                        // ~136 MB total
    k_sentinel<<<1, 8, 0, stream>>>(out);   // absmax ~1e6 => ws_size too small
    return;
  }

  hipMemsetAsync(cur, 0, (size_t)N_NODES * 4, stream);

  // CSR by dst (deterministic structure; intra-node order via atomics, fp-order noise only)
  k_hist<<<(N_EDGES + 255) / 256, 256, 0, stream>>>(ei, cur);
  const int nsb = (N_NODES + 1023) / 1024;
  k_scan1<<<nsb, 1024, 0, stream>>>(cur, offp, bsum);
  k_scan2<<<1, 64, 0, stream>>>(bsum, nsb);
  k_scan3<<<(N_NODES + 255) / 256, 256, 0, stream>>>(offp, bsum);
  k_fill<<<(N_EDGES + 255) / 256, 256, 0, stream>>>(ei, ea, offp, cur, csr);

  k_wc1<<<(NLAYER * W1ROWS * KP1 + 255) / 256, 256, 0, stream>>>(w1, w1b);
  k_wc2<<<(NLAYER * WID2 * W1ROWS + 255) / 256, 256, 0, stream>>>(w2, w2b);
  k_wch<<<(512 * KP1 + 255) / 256, 256, 0, stream>>>(hw1, hw1b);
  k_comb<<<(NLAYER * 10 * HPAD + 255) / 256, 256, 0, stream>>>(ee1, ee2, comb);
  k_nemb<<<(N_NODES * 38 + 255) / 256, 256, 0, stream>>>(x, ae1, ae2, h);

  const int mlpBlocks = (N_NODES + MROWS - 1) / MROWS;   // 1563
  for (int l = 0; l < NLAYER; ++l) {
    k_agg<<<(N_NODES + 3) / 4, 256, 0, stream>>>(h, aggb, csr, offp, comb + l * 10 * HPAD);
    k_mlp<<<mlpBlocks, 512, 0, stream>>>(aggb,
        w1b + (size_t)l * W1ROWS * KP1, w2b + (size_t)l * WID2 * W1ROWS,
        b1 + l * 600, b2 + l * DIMD,
        bng + l * DIMD, bnbp + l * DIMD, bnm + l * DIMD, bnv + l * DIMD,
        (l < NLAYER - 1) ? 1 : 0, h);
  }

  k_pool<<<N_GRAPH, KP1, 0, stream>>>(h, batch, pooled);
  k_head<<<N_GRAPH / HGR, 256, 0, stream>>>(pooled, hw1b, hb1, hw2, hb2, out);
}

// Round 14
// 1914.725 us; speedup vs baseline: 1.2048x; 1.2048x over previous
//
#include <hip/hip_runtime.h>
#include <hip/hip_bf16.h>
#include <stdint.h>

// Problem constants (fixed by the reference)
#define N_NODES 100000
#define N_EDGES 400000
#define N_GRAPH 4096
#define DIMD    300
#define NLAYER  5
// padded dims
#define HPAD   304   // h row stride (bf16), 38 x 8
#define KP1    320   // A-tile row width (bf16) = K of GEMM1 (5 x 64)
#define W1ROWS 640   // w1b rows; also k-stride of w2b
#define WID2   320   // w2b rows (20 n-frags of 16)
#define MROWS  64    // node rows per k_mlp block
#define HGR    64    // graphs per head block

typedef __attribute__((ext_vector_type(8))) short bf16x8_t;
typedef __attribute__((ext_vector_type(4))) float f32x4_t;

__device__ __forceinline__ void gload_lds16(const void* g, void* l) {
  auto gp = (__attribute__((address_space(1))) void*)(uintptr_t)g;
  auto lp = (__attribute__((address_space(3))) void*)(uint32_t)(uintptr_t)l;
  __builtin_amdgcn_global_load_lds(gp, lp, 16, 0, 0);
}
__device__ __forceinline__ short f2bs(float f) {
  __hip_bfloat16 b = __float2bfloat16(f); return *(short*)&b;
}
__device__ __forceinline__ float bs2f(short s) {
  __hip_bfloat16 b; *(short*)&b = s; return __bfloat162float(b);
}

// ---------------- CSR build ----------------
__global__ void k_hist(const int* __restrict__ ei, int* __restrict__ cur) {
  const int e = blockIdx.x * blockDim.x + threadIdx.x;
  if (e < N_EDGES) atomicAdd(&cur[ei[N_EDGES + e]], 1);
}

__global__ void k_scan1(int* __restrict__ cur, int* __restrict__ off, int* __restrict__ bsum) {
  __shared__ int buf[1024];
  const int tid = threadIdx.x;
  const int i = blockIdx.x * 1024 + tid;
  int v = (i < N_NODES) ? cur[i] : 0;
  buf[tid] = v;
  __syncthreads();
  for (int s = 1; s < 1024; s <<= 1) {
    int t = (tid >= s) ? buf[tid - s] : 0;
    __syncthreads();
    buf[tid] += t;
    __syncthreads();
  }
  if (i < N_NODES) { off[i + 1] = buf[tid]; cur[i] = 0; }
  if (tid == 1023) bsum[blockIdx.x] = buf[1023];
}

__global__ void k_scan2(int* __restrict__ bsum, int nb) {
  if (threadIdx.x == 0 && blockIdx.x == 0) {
    int run = 0;
    for (int b = 0; b < nb; ++b) { int v = bsum[b]; bsum[b] = run; run += v; }
  }
}

__global__ void k_scan3(int* __restrict__ off, const int* __restrict__ bsum) {
  const int i = blockIdx.x * blockDim.x + threadIdx.x;
  if (i == 0) off[0] = 0;
  if (i < N_NODES) off[i + 1] += bsum[i >> 10];
}

__global__ void k_fill(const int* __restrict__ ei, const int* __restrict__ ea,
                       const int* __restrict__ off, int* __restrict__ cur,
                       int* __restrict__ csr) {
  const int e = blockIdx.x * blockDim.x + threadIdx.x;
  if (e < N_EDGES) {
    const int d = ei[N_EDGES + e];
    const int pos = atomicAdd(&cur[d], 1);
    const int c = ea[2 * e] * 3 + ea[2 * e + 1];   // attr values in [0,3)
    csr[off[d] + pos] = (ei[e] << 4) | c;          // src<<4 | comb-index
  }
}

// ---------------- small precompute ----------------
// comb[l][r][0..HPAD): r<9 -> ee1[l][r/3]+ee2[l][r%3]; r==9 -> self-loop; pad cols 0
__global__ void k_comb(const float* __restrict__ e1, const float* __restrict__ e2,
                       float* __restrict__ comb) {
  const int idx = blockIdx.x * blockDim.x + threadIdx.x;
  if (idx >= NLAYER * 10 * HPAD) return;
  const int l = idx / (10 * HPAD);
  const int r = (idx / HPAD) % 10;
  const int d = idx % HPAD;
  float v = 0.f;
  if (d < DIMD) {
    int a, b;
    if (r < 9) { a = r / 3; b = r % 3; } else { a = 4; b = 0; }
    v = e1[(l * 6 + a) * DIMD + d] + e2[(l * 3 + b) * DIMD + d];
  }
  comb[idx] = v;
}

// w1 (L,300,600) f32 -> w1b (L,[640 n][320 k]) bf16, zero-padded
__global__ void k_wc1(const float* __restrict__ w, __hip_bfloat16* __restrict__ wb) {
  const int idx = blockIdx.x * blockDim.x + threadIdx.x;
  if (idx >= NLAYER * W1ROWS * KP1) return;
  const int l = idx / (W1ROWS * KP1);
  const int n = (idx / KP1) % W1ROWS;
  const int k = idx % KP1;
  float v = 0.f;
  if (n < 600 && k < DIMD) v = w[((long)l * DIMD + k) * 600 + n];
  wb[idx] = __float2bfloat16(v);
}

// w2 (L,600,300) f32 -> w2b (L,[320 n][640 k]) bf16, zero-padded
__global__ void k_wc2(const float* __restrict__ w, __hip_bfloat16* __restrict__ wb) {
  const int idx = blockIdx.x * blockDim.x + threadIdx.x;
  if (idx >= NLAYER * WID2 * W1ROWS) return;
  const int l = idx / (WID2 * W1ROWS);
  const int n = (idx / W1ROWS) % WID2;
  const int k = idx % W1ROWS;
  float v = 0.f;
  if (n < DIMD && k < 600) v = w[((long)l * 600 + k) * DIMD + n];
  wb[idx] = __float2bfloat16(v);
}

// head w1 (300,512) f32 -> hw1b [512 n][320 k] bf16, zero-padded
__global__ void k_wch(const float* __restrict__ w, __hip_bfloat16* __restrict__ wb) {
  const int idx = blockIdx.x * blockDim.x + threadIdx.x;
  if (idx >= 512 * KP1) return;
  const int n = idx / KP1;
  const int k = idx % KP1;
  float v = (k < DIMD) ? w[(long)k * 512 + n] : 0.f;
  wb[idx] = __float2bfloat16(v);
}

// node input embedding -> bf16 h (one 16B chunk per thread)
__global__ void k_nemb(const int* __restrict__ x, const float* __restrict__ ae1,
                       const float* __restrict__ ae2, __hip_bfloat16* __restrict__ h) {
  const int gid = blockIdx.x * blockDim.x + threadIdx.x;
  if (gid >= N_NODES * 38) return;
  const int node = gid / 38;
  const int l = gid % 38;
  bf16x8_t ov;
#pragma unroll
  for (int j = 0; j < 8; ++j) ov[j] = 0;
  {
    const int i0 = x[2 * node], i1 = x[2 * node + 1];
    const float* r1 = ae1 + (long)i0 * DIMD + l * 8;
    const float* r2 = ae2 + (long)i1 * DIMD + l * 8;
#pragma unroll
    for (int j = 0; j < 8; ++j) {
      const int d = l * 8 + j;
      if (d < DIMD) ov[j] = f2bs(r1[j] + r2[j]);
    }
  }
  *(bf16x8_t*)(h + (long)node * HPAD + l * 8) = ov;
}

// ---------------- fused GIN layer: gather + MLP + BN, h_in -> h_out ----------------
// R11's 204-us MLP body (64-row tile, 4 waves, 10 half-chunks, 48 KB LDS, 3 blocks/CU)
// with the A-staging replaced by an in-kernel CSR gather (k_agg fused away).
// Each wave builds 16 A-rows: acc = h[node] + comb[9] + sum_e (h[src_e] + comb[c_e]),
// written bf16 into the swizzled As layout. Cross-block phase skew hides gather latency.
// h ping-pong (hin != hout) avoids the read/write race on h.
__global__ __launch_bounds__(256)
void k_mlp(const __hip_bfloat16* __restrict__ hin,
           const int* __restrict__ csr, const int* __restrict__ off,
           const float* __restrict__ comb,           // [10][HPAD] for this layer
           const __hip_bfloat16* __restrict__ w1b,   // [640][320]
           const __hip_bfloat16* __restrict__ w2b,   // [320][640]
           const float* __restrict__ b1,             // [600]
           const float* __restrict__ b2,             // [300]
           const float* __restrict__ bng, const float* __restrict__ bnb,
           const float* __restrict__ bnm, const float* __restrict__ bnv,
           int reluFlag,
           __hip_bfloat16* __restrict__ hout) {
  __shared__ __align__(16) char As[MROWS * 640];   // 40 KB, swizzled
  __shared__ __align__(16) char P[MROWS * 128];    // 8 KB: 64 rows x 64 bf16, swizzled
  const int tid = threadIdx.x;
  const int lane = tid & 63;
  const int wv = tid >> 6;         // 0..3
  const int fr = lane & 15;
  const int kg = lane >> 4;        // 0..3
  const int row0 = blockIdx.x * MROWS;

  // ---- gather phase: wave wv builds A-rows wv*16 .. wv*16+15 ----
  {
    const bool act = lane < 38;    // 38 granules cover HPAD=304 input cols
    for (int i = 0; i < 16; ++i) {
      const int r = wv * 16 + i;   // local row
      int node = row0 + r;
      if (node >= N_NODES) node = N_NODES - 1;   // clamp (dup row; stores guarded later)
      float acc[8];
      if (act) {
        const bf16x8_t hv = *(const bf16x8_t*)(hin + (size_t)node * HPAD + lane * 8);
        const float* c9 = comb + 9 * HPAD + lane * 8;
#pragma unroll
        for (int j = 0; j < 8; ++j) acc[j] = bs2f(hv[j]) + c9[j];  // h + self_emb
      } else {
#pragma unroll
        for (int j = 0; j < 8; ++j) acc[j] = 0.f;
      }
      const int p0 = off[node], p1 = off[node + 1];
      int p = p0;
      for (; p + 1 < p1; p += 2) {           // 2x unroll: two gathers in flight
        const int v0 = csr[p], v1 = csr[p + 1];
        if (act) {
          const bf16x8_t h0 = *(const bf16x8_t*)(hin + (size_t)(v0 >> 4) * HPAD + lane * 8);
          const bf16x8_t h1 = *(const bf16x8_t*)(hin + (size_t)(v1 >> 4) * HPAD + lane * 8);
          const float* c0 = comb + (v0 & 15) * HPAD + lane * 8;
          const float* c1 = comb + (v1 & 15) * HPAD + lane * 8;
#pragma unroll
          for (int j = 0; j < 8; ++j) acc[j] += bs2f(h0[j]) + c0[j];
#pragma unroll
          for (int j = 0; j < 8; ++j) acc[j] += bs2f(h1[j]) + c1[j];
        }
      }
      if (p < p1) {
        const int v0 = csr[p];
        if (act) {
          const bf16x8_t h0 = *(const bf16x8_t*)(hin + (size_t)(v0 >> 4) * HPAD + lane * 8);
          const float* c0 = comb + (v0 & 15) * HPAD + lane * 8;
#pragma unroll
          for (int j = 0; j < 8; ++j) acc[j] += bs2f(h0[j]) + c0[j];
        }
      }
      if (lane < 40) {                       // 40 granules = 320 cols (304..319 zero)
        bf16x8_t ov;
#pragma unroll
        for (int j = 0; j < 8; ++j) ov[j] = act ? f2bs(acc[j]) : (short)0;
        *(bf16x8_t*)(As + r * 640 + ((lane ^ (r & 7)) * 16)) = ov;  // swizzled slot
      }
    }
  }

  f32x4_t accB[4][5];
#pragma unroll
  for (int m = 0; m < 4; ++m)
#pragma unroll
    for (int n = 0; n < 5; ++n) accB[m][n] = (f32x4_t){0.f, 0.f, 0.f, 0.f};

  __syncthreads();   // A built

  // ---- ten 64-col half-chunks: phaseA(hc) -> P ; phaseB(hc) accumulates accB ----
  for (int hc = 0; hc < 10; ++hc) {
    // phase A: accA[m] = A(64x320) @ w1 slice (320 x 16 cols of this wave)
    f32x4_t accA[4];
#pragma unroll
    for (int m = 0; m < 4; ++m) accA[m] = (f32x4_t){0.f, 0.f, 0.f, 0.f};
    const __hip_bfloat16* w1c = w1b + (size_t)(hc * 64 + wv * 16) * KP1;
#pragma unroll
    for (int ks = 0; ks < 10; ++ks) {
      const int k2 = ks * 64 + kg * 16;
      bf16x8_t af[4];
#pragma unroll
      for (int m = 0; m < 4; ++m) {
        const int r = m * 16 + fr;
        af[m] = *(const bf16x8_t*)(As + r * 640 + (k2 ^ ((r & 7) << 4)));
      }
      const bf16x8_t bfr = *(const bf16x8_t*)(w1c + (size_t)fr * KP1 + ks * 32 + kg * 8);
#pragma unroll
      for (int m = 0; m < 4; ++m)
        accA[m] = __builtin_amdgcn_mfma_f32_16x16x32_bf16(af[m], bfr, accA[m], 0, 0, 0);
    }
    const int col = hc * 64 + wv * 16 + fr;       // global hidden col of this lane
    const float bv = (col < 600) ? b1[col] : 0.f;

    __syncthreads();   // previous half-chunk's phase B finished reading P
#pragma unroll
    for (int m = 0; m < 4; ++m)
#pragma unroll
      for (int j = 0; j < 4; ++j) {
        const int prow = m * 16 + kg * 4 + j;
        const int pcol = wv * 16 + fr;            // 0..63 within half-chunk
        *(short*)(P + prow * 128 + ((pcol * 2) ^ ((prow & 7) << 4))) =
            f2bs(fmaxf(accA[m][j] + bv, 0.f));
      }
    __syncthreads();   // P ready

    // phase B: accB += P(64x64) @ w2 slice (64 k x 320 n)
#pragma unroll
    for (int ks = 0; ks < 2; ++ks) {
      bf16x8_t af2[4], bf2[5];
#pragma unroll
      for (int m = 0; m < 4; ++m) {
        const int pr = m * 16 + fr;
        af2[m] = *(const bf16x8_t*)(P + pr * 128 + ((ks * 64 + kg * 16) ^ ((pr & 7) << 4)));
      }
      const int k2 = hc * 64 + ks * 32 + kg * 8;
#pragma unroll
      for (int n = 0; n < 5; ++n)
        bf2[n] = *(const bf16x8_t*)(w2b + (size_t)(wv * 80 + n * 16 + fr) * W1ROWS + k2);
#pragma unroll
      for (int m = 0; m < 4; ++m)
#pragma unroll
        for (int n = 0; n < 5; ++n)
          accB[m][n] = __builtin_amdgcn_mfma_f32_16x16x32_bf16(af2[m], bf2[n], accB[m][n], 0, 0, 0);
    }
  }

  // ---- epilogue: hout = BN(accB + b2)(+relu), bf16, col 300..303 -> 0 ----
  float scale[5], shift[5];
#pragma unroll
  for (int n = 0; n < 5; ++n) {
    const int col = wv * 80 + n * 16 + fr;
    if (col < DIMD) {
      const float sc = rsqrtf(bnv[col] + 1e-5f) * bng[col];
      scale[n] = sc;
      shift[n] = (b2[col] - bnm[col]) * sc + bnb[col];
    } else { scale[n] = 0.f; shift[n] = 0.f; }
  }
#pragma unroll
  for (int m = 0; m < 4; ++m) {
#pragma unroll
    for (int n = 0; n < 5; ++n) {
      const int col = wv * 80 + n * 16 + fr;
      if (col >= HPAD) continue;
#pragma unroll
      for (int j = 0; j < 4; ++j) {
        const int node = row0 + m * 16 + kg * 4 + j;
        if (node >= N_NODES) continue;
        float v = 0.f;
        if (col < DIMD) {
          v = accB[m][n][j] * scale[n] + shift[n];
          if (reluFlag) v = fmaxf(v, 0.f);
        }
        hout[(size_t)node * HPAD + col] = __float2bfloat16(v);
      }
    }
  }
}

// ---------------- pooling (batch sorted -> binary search), bf16 out ----------------
__device__ __forceinline__ int lbound(const int* a, int n, int key) {
  int lo = 0, hi = n;
  while (lo < hi) { int mid = (lo + hi) >> 1; if (a[mid] < key) lo = mid + 1; else hi = mid; }
  return lo;
}

__global__ void k_pool(const __hip_bfloat16* __restrict__ h, const int* __restrict__ batch,
                       __hip_bfloat16* __restrict__ pooled) {
  __shared__ int se[2];
  const int g = blockIdx.x;
  if (threadIdx.x < 2) se[threadIdx.x] = lbound(batch, N_NODES, g + threadIdx.x);
  __syncthreads();
  const int d = threadIdx.x;
  if (d < KP1) {
    float a = 0.f;
    if (d < DIMD)
      for (int i = se[0]; i < se[1]; ++i) a += __bfloat162float(h[(long)i * HPAD + d]);
    pooled[(long)g * KP1 + d] = __float2bfloat16(d < DIMD ? a : 0.f);
  }
}

// ---------------- MFMA head: out = relu(pooled@hw1+hb1)@hw2+hb2 ----------------
__global__ __launch_bounds__(256)
void k_head(const __hip_bfloat16* __restrict__ pooled,  // [4096][320] bf16
            const __hip_bfloat16* __restrict__ hw1b,    // [512][320] bf16
            const float* __restrict__ hb1, const float* __restrict__ hw2,
            const float* __restrict__ hb2, float* __restrict__ out) {
  __shared__ __align__(16) char As[HGR * 640];   // 40 KB
  __shared__ float sred[4][HGR][2];
  const int tid = threadIdx.x;
  const int lane = tid & 63;
  const int wc = tid >> 6;
  const int fr = lane & 15;
  const int kg = lane >> 4;
  const int g0 = blockIdx.x * HGR;

#pragma unroll
  for (int it = 0; it < 10; ++it) {
    const int g = it * 256 + tid;
    const int r = g / 40;
    const int gin = g - r * 40;
    gload_lds16((const char*)pooled + (size_t)(g0 + r) * 640 + (size_t)((gin ^ (r & 7)) * 16),
                As + g * 16);
  }

  f32x4_t acc[4][8];
#pragma unroll
  for (int m = 0; m < 4; ++m)
#pragma unroll
    for (int n = 0; n < 8; ++n) acc[m][n] = (f32x4_t){0.f, 0.f, 0.f, 0.f};

  __syncthreads();

#pragma unroll
  for (int ks = 0; ks < 10; ++ks) {
    const int k2 = ks * 64 + kg * 16;
    bf16x8_t af[4], bw[8];
#pragma unroll
    for (int m = 0; m < 4; ++m) {
      const int r = m * 16 + fr;
      af[m] = *(const bf16x8_t*)(As + r * 640 + (k2 ^ ((r & 7) << 4)));
    }
#pragma unroll
    for (int n = 0; n < 8; ++n)
      bw[n] = *(const bf16x8_t*)(hw1b + (size_t)(wc * 128 + n * 16 + fr) * KP1 + ks * 32 + kg * 8);
#pragma unroll
    for (int m = 0; m < 4; ++m)
#pragma unroll
      for (int n = 0; n < 8; ++n)
        acc[m][n] = __builtin_amdgcn_mfma_f32_16x16x32_bf16(af[m], bw[n], acc[m][n], 0, 0, 0);
  }

  float p0[4][4], p1[4][4];
#pragma unroll
  for (int m = 0; m < 4; ++m)
#pragma unroll
    for (int j = 0; j < 4; ++j) { p0[m][j] = 0.f; p1[m][j] = 0.f; }
#pragma unroll
  for (int n = 0; n < 8; ++n) {
    const int col = wc * 128 + n * 16 + fr;
    const float bv = hb1[col];
    const float wa = hw2[2 * col], wb = hw2[2 * col + 1];
#pragma unroll
    for (int m = 0; m < 4; ++m)
#pragma unroll
      for (int j = 0; j < 4; ++j) {
        const float z = fmaxf(acc[m][n][j] + bv, 0.f);
        p0[m][j] = fmaf(z, wa, p0[m][j]);
        p1[m][j] = fmaf(z, wb, p1[m][j]);
      }
  }
#pragma unroll
  for (int m = 0; m < 4; ++m)
#pragma unroll
    for (int j = 0; j < 4; ++j) {
#pragma unroll
      for (int s = 1; s < 16; s <<= 1) {
        p0[m][j] += __shfl_xor(p0[m][j], s, 64);
        p1[m][j] += __shfl_xor(p1[m][j], s, 64);
      }
    }
  if (fr == 0) {
#pragma unroll
    for (int m = 0; m < 4; ++m)
#pragma unroll
      for (int j = 0; j < 4; ++j) {
        const int row = m * 16 + kg * 4 + j;
        sred[wc][row][0] = p0[m][j];
        sred[wc][row][1] = p1[m][j];
      }
  }
  __syncthreads();
  if (tid < HGR) {
    const int row = tid;
    float a0 = sred[0][row][0] + sred[1][row][0] + sred[2][row][0] + sred[3][row][0];
    float a1 = sred[0][row][1] + sred[1][row][1] + sred[2][row][1] + sred[3][row][1];
    out[2 * (g0 + row)] = a0 + hb2[0];
    out[2 * (g0 + row) + 1] = a1 + hb2[1];
  }
}

// sentinel: signal "workspace too small" through the only visible channel
__global__ void k_sentinel(float* out) { out[threadIdx.x] = 1.0e6f; }

// ---------------- launch ----------------
extern "C" void kernel_launch(void* const* d_in, const int* in_sizes, int n_in,
                              void* d_out, int out_size, void* d_ws, size_t ws_size,
                              hipStream_t stream) {
  const int*   x     = (const int*)d_in[0];
  const int*   ei    = (const int*)d_in[1];
  const int*   ea    = (const int*)d_in[2];
  const int*   batch = (const int*)d_in[3];
  const float* ae1   = (const float*)d_in[4];
  const float* ae2   = (const float*)d_in[5];
  const float* ee1   = (const float*)d_in[6];
  const float* ee2   = (const float*)d_in[7];
  const float* w1    = (const float*)d_in[8];
  const float* b1    = (const float*)d_in[9];
  const float* w2    = (const float*)d_in[10];
  const float* b2    = (const float*)d_in[11];
  const float* bng   = (const float*)d_in[12];
  const float* bnbp  = (const float*)d_in[13];
  const float* bnm   = (const float*)d_in[14];
  const float* bnv   = (const float*)d_in[15];
  const float* hw1   = (const float*)d_in[16];
  const float* hb1   = (const float*)d_in[17];
  const float* hw2   = (const float*)d_in[18];
  const float* hb2   = (const float*)d_in[19];
  float* out = (float*)d_out;

  char* ws = (char*)d_ws;
  size_t o = 0;
  auto alloc = [&](size_t bytes) { size_t p = o; o += (bytes + 255) & ~(size_t)255; return p; };
  __hip_bfloat16* h1     = (__hip_bfloat16*)(ws + alloc((size_t)N_NODES * HPAD * 2));   // 60.8 MB
  __hip_bfloat16* h2     = (__hip_bfloat16*)(ws + alloc((size_t)N_NODES * HPAD * 2));   // 60.8 MB
  __hip_bfloat16* w1b    = (__hip_bfloat16*)(ws + alloc((size_t)NLAYER * W1ROWS * KP1 * 2));
  __hip_bfloat16* w2b    = (__hip_bfloat16*)(ws + alloc((size_t)NLAYER * WID2 * W1ROWS * 2));
  __hip_bfloat16* hw1b   = (__hip_bfloat16*)(ws + alloc((size_t)512 * KP1 * 2));
  float*          comb   = (float*)         (ws + alloc((size_t)NLAYER * 10 * HPAD * 4));
  int*            offp   = (int*)           (ws + alloc((size_t)(N_NODES + 1) * 4));
  int*            cur    = (int*)           (ws + alloc((size_t)N_NODES * 4));
  int*            csr    = (int*)           (ws + alloc((size_t)N_EDGES * 4));
  __hip_bfloat16* pooled = (__hip_bfloat16*)(ws + alloc((size_t)N_GRAPH * KP1 * 2));
  int*            bsum   = (int*)           (ws + alloc(128 * 4));
  if (o > ws_size) {                        // ~132 MB total
    k_sentinel<<<1, 8, 0, stream>>>(out);   // absmax ~1e6 => ws_size too small
    return;
  }

  hipMemsetAsync(cur, 0, (size_t)N_NODES * 4, stream);

  // CSR by dst (deterministic structure; intra-node order via atomics, fp-order noise only)
  k_hist<<<(N_EDGES + 255) / 256, 256, 0, stream>>>(ei, cur);
  const int nsb = (N_NODES + 1023) / 1024;
  k_scan1<<<nsb, 1024, 0, stream>>>(cur, offp, bsum);
  k_scan2<<<1, 64, 0, stream>>>(bsum, nsb);
  k_scan3<<<(N_NODES + 255) / 256, 256, 0, stream>>>(offp, bsum);
  k_fill<<<(N_EDGES + 255) / 256, 256, 0, stream>>>(ei, ea, offp, cur, csr);

  k_wc1<<<(NLAYER * W1ROWS * KP1 + 255) / 256, 256, 0, stream>>>(w1, w1b);
  k_wc2<<<(NLAYER * WID2 * W1ROWS + 255) / 256, 256, 0, stream>>>(w2, w2b);
  k_wch<<<(512 * KP1 + 255) / 256, 256, 0, stream>>>(hw1, hw1b);
  k_comb<<<(NLAYER * 10 * HPAD + 255) / 256, 256, 0, stream>>>(ee1, ee2, comb);
  k_nemb<<<(N_NODES * 38 + 255) / 256, 256, 0, stream>>>(x, ae1, ae2, h1);

  const int mlpBlocks = (N_NODES + MROWS - 1) / MROWS;   // 1563
  const __hip_bfloat16* hc = h1;
  __hip_bfloat16* hn = h2;
  for (int l = 0; l < NLAYER; ++l) {
    k_mlp<<<mlpBlocks, 256, 0, stream>>>(hc, csr, offp, comb + l * 10 * HPAD,
        w1b + (size_t)l * W1ROWS * KP1, w2b + (size_t)l * WID2 * W1ROWS,
        b1 + l * 600, b2 + l * DIMD,
        bng + l * DIMD, bnbp + l * DIMD, bnm + l * DIMD, bnv + l * DIMD,
        (l < NLAYER - 1) ? 1 : 0, hn);
    const __hip_bfloat16* t = hc; hc = hn; hn = (__hip_bfloat16*)t;
  }

  k_pool<<<N_GRAPH, KP1, 0, stream>>>(hc, batch, pooled);
  k_head<<<N_GRAPH / HGR, 256, 0, stream>>>(pooled, hw1b, hb1, hw2, hb2, out);
}

// Round 15
// 1472.809 us; speedup vs baseline: 1.5662x; 1.3000x over previous
//
#include <hip/hip_runtime.h>
#include <hip/hip_bf16.h>
#include <stdint.h>

// Problem constants (fixed by the reference)
#define N_NODES 100000
#define N_EDGES 400000
#define N_GRAPH 4096
#define DIMD    300
#define NLAYER  5
// padded dims
#define HPAD   304   // h row stride (bf16), 38 x 8
#define KP1    320   // aggb row stride = K of GEMM1 (5 x 64)
#define W1ROWS 640   // w1b rows; also k-stride of w2b
#define WID2   320   // w2b rows (20 n-frags of 16)
#define MROWS  64    // node rows per k_mlp block
#define HGR    64    // graphs per head block

typedef __attribute__((ext_vector_type(8))) short bf16x8_t;
typedef __attribute__((ext_vector_type(4))) float f32x4_t;

__device__ __forceinline__ void gload_lds16(const void* g, void* l) {
  auto gp = (__attribute__((address_space(1))) void*)(uintptr_t)g;
  auto lp = (__attribute__((address_space(3))) void*)(uint32_t)(uintptr_t)l;
  __builtin_amdgcn_global_load_lds(gp, lp, 16, 0, 0);
}
__device__ __forceinline__ short f2bs(float f) {
  __hip_bfloat16 b = __float2bfloat16(f); return *(short*)&b;
}
__device__ __forceinline__ float bs2f(short s) {
  __hip_bfloat16 b; *(short*)&b = s; return __bfloat162float(b);
}

// ---------------- CSR build ----------------
__global__ void k_hist(const int* __restrict__ ei, int* __restrict__ cur) {
  const int e = blockIdx.x * blockDim.x + threadIdx.x;
  if (e < N_EDGES) atomicAdd(&cur[ei[N_EDGES + e]], 1);
}

__global__ void k_scan1(int* __restrict__ cur, int* __restrict__ off, int* __restrict__ bsum) {
  __shared__ int buf[1024];
  const int tid = threadIdx.x;
  const int i = blockIdx.x * 1024 + tid;
  int v = (i < N_NODES) ? cur[i] : 0;
  buf[tid] = v;
  __syncthreads();
  for (int s = 1; s < 1024; s <<= 1) {
    int t = (tid >= s) ? buf[tid - s] : 0;
    __syncthreads();
    buf[tid] += t;
    __syncthreads();
  }
  if (i < N_NODES) { off[i + 1] = buf[tid]; cur[i] = 0; }
  if (tid == 1023) bsum[blockIdx.x] = buf[1023];
}

__global__ void k_scan2(int* __restrict__ bsum, int nb) {
  if (threadIdx.x == 0 && blockIdx.x == 0) {
    int run = 0;
    for (int b = 0; b < nb; ++b) { int v = bsum[b]; bsum[b] = run; run += v; }
  }
}

__global__ void k_scan3(int* __restrict__ off, const int* __restrict__ bsum) {
  const int i = blockIdx.x * blockDim.x + threadIdx.x;
  if (i == 0) off[0] = 0;
  if (i < N_NODES) off[i + 1] += bsum[i >> 10];
}

__global__ void k_fill(const int* __restrict__ ei, const int* __restrict__ ea,
                       const int* __restrict__ off, int* __restrict__ cur,
                       int* __restrict__ csr) {
  const int e = blockIdx.x * blockDim.x + threadIdx.x;
  if (e < N_EDGES) {
    const int d = ei[N_EDGES + e];
    const int pos = atomicAdd(&cur[d], 1);
    const int c = ea[2 * e] * 3 + ea[2 * e + 1];   // attr values in [0,3)
    csr[off[d] + pos] = (ei[e] << 4) | c;          // src<<4 | comb-index
  }
}

// ---------------- small precompute ----------------
// comb[l][r][0..HPAD): r<9 -> ee1[l][r/3]+ee2[l][r%3]; r==9 -> self-loop; pad cols 0
__global__ void k_comb(const float* __restrict__ e1, const float* __restrict__ e2,
                       float* __restrict__ comb) {
  const int idx = blockIdx.x * blockDim.x + threadIdx.x;
  if (idx >= NLAYER * 10 * HPAD) return;
  const int l = idx / (10 * HPAD);
  const int r = (idx / HPAD) % 10;
  const int d = idx % HPAD;
  float v = 0.f;
  if (d < DIMD) {
    int a, b;
    if (r < 9) { a = r / 3; b = r % 3; } else { a = 4; b = 0; }
    v = e1[(l * 6 + a) * DIMD + d] + e2[(l * 3 + b) * DIMD + d];
  }
  comb[idx] = v;
}

// w1 (L,300,600) f32 -> w1b (L,[640 n][320 k]) bf16, zero-padded
__global__ void k_wc1(const float* __restrict__ w, __hip_bfloat16* __restrict__ wb) {
  const int idx = blockIdx.x * blockDim.x + threadIdx.x;
  if (idx >= NLAYER * W1ROWS * KP1) return;
  const int l = idx / (W1ROWS * KP1);
  const int n = (idx / KP1) % W1ROWS;
  const int k = idx % KP1;
  float v = 0.f;
  if (n < 600 && k < DIMD) v = w[((long)l * DIMD + k) * 600 + n];
  wb[idx] = __float2bfloat16(v);
}

// w2 (L,600,300) f32 -> w2b (L,[320 n][640 k]) bf16, zero-padded
__global__ void k_wc2(const float* __restrict__ w, __hip_bfloat16* __restrict__ wb) {
  const int idx = blockIdx.x * blockDim.x + threadIdx.x;
  if (idx >= NLAYER * WID2 * W1ROWS) return;
  const int l = idx / (WID2 * W1ROWS);
  const int n = (idx / W1ROWS) % WID2;
  const int k = idx % W1ROWS;
  float v = 0.f;
  if (n < DIMD && k < 600) v = w[((long)l * 600 + k) * DIMD + n];
  wb[idx] = __float2bfloat16(v);
}

// head w1 (300,512) f32 -> hw1b [512 n][320 k] bf16, zero-padded
__global__ void k_wch(const float* __restrict__ w, __hip_bfloat16* __restrict__ wb) {
  const int idx = blockIdx.x * blockDim.x + threadIdx.x;
  if (idx >= 512 * KP1) return;
  const int n = idx / KP1;
  const int k = idx % KP1;
  float v = (k < DIMD) ? w[(long)k * 512 + n] : 0.f;
  wb[idx] = __float2bfloat16(v);
}

// node input embedding -> bf16 h (one 16B chunk per thread)
__global__ void k_nemb(const int* __restrict__ x, const float* __restrict__ ae1,
                       const float* __restrict__ ae2, __hip_bfloat16* __restrict__ h) {
  const int gid = blockIdx.x * blockDim.x + threadIdx.x;
  if (gid >= N_NODES * 38) return;
  const int node = gid / 38;
  const int l = gid % 38;
  bf16x8_t ov;
#pragma unroll
  for (int j = 0; j < 8; ++j) ov[j] = 0;
  {
    const int i0 = x[2 * node], i1 = x[2 * node + 1];
    const float* r1 = ae1 + (long)i0 * DIMD + l * 8;
    const float* r2 = ae2 + (long)i1 * DIMD + l * 8;
#pragma unroll
    for (int j = 0; j < 8; ++j) {
      const int d = l * 8 + j;
      if (d < DIMD) ov[j] = f2bs(r1[j] + r2[j]);
    }
  }
  *(bf16x8_t*)(h + (long)node * HPAD + l * 8) = ov;
}

// ---------------- aggregation: thread-per-(node,granule), full lane utilization ----------------
// gid = node*40 + g; each thread owns one 16B granule of the output row and walks the
// node's CSR list (2x unrolled). All 64 lanes active (vs 40/64 in the wave-per-node form);
// loads stay coalesced (consecutive lanes = consecutive granules).
__global__ __launch_bounds__(256)
void k_agg(const __hip_bfloat16* __restrict__ h, __hip_bfloat16* __restrict__ aggb,
           const int* __restrict__ csr, const int* __restrict__ off,
           const float* __restrict__ comb) {
  const int gid = blockIdx.x * 256 + threadIdx.x;
  if (gid >= N_NODES * 40) return;
  const int node = gid / 40;
  const int g = gid - node * 40;          // granule 0..39
  const bool act = g < 38;                // granules 38,39 are K-pad (zeros)
  float acc[8];
  if (act) {
    const bf16x8_t hv = *(const bf16x8_t*)(h + (size_t)node * HPAD + g * 8);
    const float* c9 = comb + 9 * HPAD + g * 8;
#pragma unroll
    for (int j = 0; j < 8; ++j) acc[j] = bs2f(hv[j]) + c9[j];  // h + self_emb
  } else {
#pragma unroll
    for (int j = 0; j < 8; ++j) acc[j] = 0.f;
  }
  const int p0 = off[node], p1 = off[node + 1];
  int p = p0;
  for (; p + 1 < p1; p += 2) {            // 2x unroll: two gathers in flight
    const int v0 = csr[p], v1 = csr[p + 1];
    if (act) {
      const bf16x8_t h0 = *(const bf16x8_t*)(h + (size_t)(v0 >> 4) * HPAD + g * 8);
      const bf16x8_t h1 = *(const bf16x8_t*)(h + (size_t)(v1 >> 4) * HPAD + g * 8);
      const float* c0 = comb + (v0 & 15) * HPAD + g * 8;
      const float* c1 = comb + (v1 & 15) * HPAD + g * 8;
#pragma unroll
      for (int j = 0; j < 8; ++j) acc[j] += bs2f(h0[j]) + c0[j];
#pragma unroll
      for (int j = 0; j < 8; ++j) acc[j] += bs2f(h1[j]) + c1[j];
    }
  }
  if (p < p1) {
    const int v0 = csr[p];
    if (act) {
      const bf16x8_t h0 = *(const bf16x8_t*)(h + (size_t)(v0 >> 4) * HPAD + g * 8);
      const float* c0 = comb + (v0 & 15) * HPAD + g * 8;
#pragma unroll
      for (int j = 0; j < 8; ++j) acc[j] += bs2f(h0[j]) + c0[j];
    }
  }
  bf16x8_t ov;
#pragma unroll
  for (int j = 0; j < 8; ++j) ov[j] = act ? f2bs(acc[j]) : (short)0;
  *(bf16x8_t*)(aggb + (size_t)node * KP1 + g * 8) = ov;   // cols 304..319 = 0
}

// ---------------- fused MLP: 64-row tile, 64-col half-chunks, 3 blocks/CU (R11) ----------------
// 256 threads = 4 waves (4 col-groups of 16); A staged once in LDS (40 KB, swizzled);
// P single buffer 64x64 bf16 (8 KB, swizzled) -> LDS 48 KB -> 3 blocks/CU = 12 waves/CU.
// Per wave: 4 m-frags per weight load (best-known ratio; schedule ledger R5..R14 all worse).
__global__ __launch_bounds__(256)
void k_mlp(const __hip_bfloat16* __restrict__ aggb,
           const __hip_bfloat16* __restrict__ w1b,   // [640][320]
           const __hip_bfloat16* __restrict__ w2b,   // [320][640]
           const float* __restrict__ b1,             // [600]
           const float* __restrict__ b2,             // [300]
           const float* __restrict__ bng, const float* __restrict__ bnb,
           const float* __restrict__ bnm, const float* __restrict__ bnv,
           int reluFlag,
           __hip_bfloat16* __restrict__ h) {
  __shared__ __align__(16) char As[MROWS * 640];   // 40 KB, swizzled
  __shared__ __align__(16) char P[MROWS * 128];    // 8 KB: 64 rows x 64 bf16, swizzled
  const int tid = threadIdx.x;
  const int lane = tid & 63;
  const int wv = tid >> 6;         // 0..3: col-group (16 hidden cols each)
  const int fr = lane & 15;
  const int kg = lane >> 4;        // 0..3
  const int row0 = blockIdx.x * MROWS;

  // ---- stage A-tile once: LDS granule (r,gin) <- global granule (gin ^ (r&7)) ----
#pragma unroll
  for (int it = 0; it < 10; ++it) {
    const int g = it * 256 + tid;          // 64 rows x 40 granules
    const int r = g / 40;
    const int gin = g - r * 40;
    int ar = row0 + r;
    if (ar >= N_NODES) ar = N_NODES - 1;   // clamp; stores are guarded
    gload_lds16((const char*)aggb + (size_t)ar * 640 + (size_t)((gin ^ (r & 7)) * 16),
                As + g * 16);
  }

  f32x4_t accB[4][5];
#pragma unroll
  for (int m = 0; m < 4; ++m)
#pragma unroll
    for (int n = 0; n < 5; ++n) accB[m][n] = (f32x4_t){0.f, 0.f, 0.f, 0.f};

  __syncthreads();   // A staged (vmcnt drained by syncthreads semantics)

  // ---- ten 64-col half-chunks: phaseA(hc) -> P ; phaseB(hc) accumulates accB ----
  for (int hc = 0; hc < 10; ++hc) {
    // phase A: accA[m] = A(64x320) @ w1 slice (320 x 16 cols of this wave)
    f32x4_t accA[4];
#pragma unroll
    for (int m = 0; m < 4; ++m) accA[m] = (f32x4_t){0.f, 0.f, 0.f, 0.f};
    const __hip_bfloat16* w1c = w1b + (size_t)(hc * 64 + wv * 16) * KP1;
#pragma unroll
    for (int ks = 0; ks < 10; ++ks) {
      const int k2 = ks * 64 + kg * 16;
      bf16x8_t af[4];
#pragma unroll
      for (int m = 0; m < 4; ++m) {
        const int r = m * 16 + fr;
        af[m] = *(const bf16x8_t*)(As + r * 640 + (k2 ^ ((r & 7) << 4)));
      }
      const bf16x8_t bfr = *(const bf16x8_t*)(w1c + (size_t)fr * KP1 + ks * 32 + kg * 8);
#pragma unroll
      for (int m = 0; m < 4; ++m)
        accA[m] = __builtin_amdgcn_mfma_f32_16x16x32_bf16(af[m], bfr, accA[m], 0, 0, 0);
    }
    const int col = hc * 64 + wv * 16 + fr;       // global hidden col of this lane
    const float bv = (col < 600) ? b1[col] : 0.f;

    __syncthreads();   // previous half-chunk's phase B finished reading P
#pragma unroll
    for (int m = 0; m < 4; ++m)
#pragma unroll
      for (int j = 0; j < 4; ++j) {
        const int prow = m * 16 + kg * 4 + j;
        const int pcol = wv * 16 + fr;            // 0..63 within half-chunk
        *(short*)(P + prow * 128 + ((pcol * 2) ^ ((prow & 7) << 4))) =
            f2bs(fmaxf(accA[m][j] + bv, 0.f));
      }
    __syncthreads();   // P ready

    // phase B: accB += P(64x64) @ w2 slice (64 k x 320 n)
#pragma unroll
    for (int ks = 0; ks < 2; ++ks) {
      bf16x8_t af2[4], bf2[5];
#pragma unroll
      for (int m = 0; m < 4; ++m) {
        const int pr = m * 16 + fr;
        af2[m] = *(const bf16x8_t*)(P + pr * 128 + ((ks * 64 + kg * 16) ^ ((pr & 7) << 4)));
      }
      const int k2 = hc * 64 + ks * 32 + kg * 8;
#pragma unroll
      for (int n = 0; n < 5; ++n)
        bf2[n] = *(const bf16x8_t*)(w2b + (size_t)(wv * 80 + n * 16 + fr) * W1ROWS + k2);
#pragma unroll
      for (int m = 0; m < 4; ++m)
#pragma unroll
        for (int n = 0; n < 5; ++n)
          accB[m][n] = __builtin_amdgcn_mfma_f32_16x16x32_bf16(af2[m], bf2[n], accB[m][n], 0, 0, 0);
    }
  }

  // ---- epilogue: h = BN(accB + b2)(+relu), bf16, col 300..303 -> 0 ----
  float scale[5], shift[5];
#pragma unroll
  for (int n = 0; n < 5; ++n) {
    const int col = wv * 80 + n * 16 + fr;
    if (col < DIMD) {
      const float sc = rsqrtf(bnv[col] + 1e-5f) * bng[col];
      scale[n] = sc;
      shift[n] = (b2[col] - bnm[col]) * sc + bnb[col];
    } else { scale[n] = 0.f; shift[n] = 0.f; }
  }
#pragma unroll
  for (int m = 0; m < 4; ++m) {
#pragma unroll
    for (int n = 0; n < 5; ++n) {
      const int col = wv * 80 + n * 16 + fr;
      if (col >= HPAD) continue;
#pragma unroll
      for (int j = 0; j < 4; ++j) {
        const int node = row0 + m * 16 + kg * 4 + j;
        if (node >= N_NODES) continue;
        float v = 0.f;
        if (col < DIMD) {
          v = accB[m][n][j] * scale[n] + shift[n];
          if (reluFlag) v = fmaxf(v, 0.f);
        }
        h[(size_t)node * HPAD + col] = __float2bfloat16(v);
      }
    }
  }
}

// ---------------- pooling (batch sorted -> binary search), bf16 out ----------------
__device__ __forceinline__ int lbound(const int* a, int n, int key) {
  int lo = 0, hi = n;
  while (lo < hi) { int mid = (lo + hi) >> 1; if (a[mid] < key) lo = mid + 1; else hi = mid; }
  return lo;
}

__global__ void k_pool(const __hip_bfloat16* __restrict__ h, const int* __restrict__ batch,
                       __hip_bfloat16* __restrict__ pooled) {
  __shared__ int se[2];
  const int g = blockIdx.x;
  if (threadIdx.x < 2) se[threadIdx.x] = lbound(batch, N_NODES, g + threadIdx.x);
  __syncthreads();
  const int d = threadIdx.x;
  if (d < KP1) {
    float a = 0.f;
    if (d < DIMD)
      for (int i = se[0]; i < se[1]; ++i) a += __bfloat162float(h[(long)i * HPAD + d]);
    pooled[(long)g * KP1 + d] = __float2bfloat16(d < DIMD ? a : 0.f);
  }
}

// ---------------- MFMA head: out = relu(pooled@hw1+hb1)@hw2+hb2 ----------------
__global__ __launch_bounds__(256)
void k_head(const __hip_bfloat16* __restrict__ pooled,  // [4096][320] bf16
            const __hip_bfloat16* __restrict__ hw1b,    // [512][320] bf16
            const float* __restrict__ hb1, const float* __restrict__ hw2,
            const float* __restrict__ hb2, float* __restrict__ out) {
  __shared__ __align__(16) char As[HGR * 640];   // 40 KB
  __shared__ float sred[4][HGR][2];
  const int tid = threadIdx.x;
  const int lane = tid & 63;
  const int wc = tid >> 6;
  const int fr = lane & 15;
  const int kg = lane >> 4;
  const int g0 = blockIdx.x * HGR;

#pragma unroll
  for (int it = 0; it < 10; ++it) {
    const int g = it * 256 + tid;
    const int r = g / 40;
    const int gin = g - r * 40;
    gload_lds16((const char*)pooled + (size_t)(g0 + r) * 640 + (size_t)((gin ^ (r & 7)) * 16),
                As + g * 16);
  }

  f32x4_t acc[4][8];
#pragma unroll
  for (int m = 0; m < 4; ++m)
#pragma unroll
    for (int n = 0; n < 8; ++n) acc[m][n] = (f32x4_t){0.f, 0.f, 0.f, 0.f};

  __syncthreads();

#pragma unroll
  for (int ks = 0; ks < 10; ++ks) {
    const int k2 = ks * 64 + kg * 16;
    bf16x8_t af[4], bw[8];
#pragma unroll
    for (int m = 0; m < 4; ++m) {
      const int r = m * 16 + fr;
      af[m] = *(const bf16x8_t*)(As + r * 640 + (k2 ^ ((r & 7) << 4)));
    }
#pragma unroll
    for (int n = 0; n < 8; ++n)
      bw[n] = *(const bf16x8_t*)(hw1b + (size_t)(wc * 128 + n * 16 + fr) * KP1 + ks * 32 + kg * 8);
#pragma unroll
    for (int m = 0; m < 4; ++m)
#pragma unroll
      for (int n = 0; n < 8; ++n)
        acc[m][n] = __builtin_amdgcn_mfma_f32_16x16x32_bf16(af[m], bw[n], acc[m][n], 0, 0, 0);
  }

  float p0[4][4], p1[4][4];
#pragma unroll
  for (int m = 0; m < 4; ++m)
#pragma unroll
    for (int j = 0; j < 4; ++j) { p0[m][j] = 0.f; p1[m][j] = 0.f; }
#pragma unroll
  for (int n = 0; n < 8; ++n) {
    const int col = wc * 128 + n * 16 + fr;
    const float bv = hb1[col];
    const float wa = hw2[2 * col], wb = hw2[2 * col + 1];
#pragma unroll
    for (int m = 0; m < 4; ++m)
#pragma unroll
      for (int j = 0; j < 4; ++j) {
        const float z = fmaxf(acc[m][n][j] + bv, 0.f);
        p0[m][j] = fmaf(z, wa, p0[m][j]);
        p1[m][j] = fmaf(z, wb, p1[m][j]);
      }
  }
#pragma unroll
  for (int m = 0; m < 4; ++m)
#pragma unroll
    for (int j = 0; j < 4; ++j) {
#pragma unroll
      for (int s = 1; s < 16; s <<= 1) {
        p0[m][j] += __shfl_xor(p0[m][j], s, 64);
        p1[m][j] += __shfl_xor(p1[m][j], s, 64);
      }
    }
  if (fr == 0) {
#pragma unroll
    for (int m = 0; m < 4; ++m)
#pragma unroll
      for (int j = 0; j < 4; ++j) {
        const int row = m * 16 + kg * 4 + j;
        sred[wc][row][0] = p0[m][j];
        sred[wc][row][1] = p1[m][j];
      }
  }
  __syncthreads();
  if (tid < HGR) {
    const int row = tid;
    float a0 = sred[0][row][0] + sred[1][row][0] + sred[2][row][0] + sred[3][row][0];
    float a1 = sred[0][row][1] + sred[1][row][1] + sred[2][row][1] + sred[3][row][1];
    out[2 * (g0 + row)] = a0 + hb2[0];
    out[2 * (g0 + row) + 1] = a1 + hb2[1];
  }
}

// sentinel: signal "workspace too small" through the only visible channel
__global__ void k_sentinel(float* out) { out[threadIdx.x] = 1.0e6f; }

// ---------------- launch ----------------
extern "C" void kernel_launch(void* const* d_in, const int* in_sizes, int n_in,
                              void* d_out, int out_size, void* d_ws, size_t ws_size,
                              hipStream_t stream) {
  const int*   x     = (const int*)d_in[0];
  const int*   ei    = (const int*)d_in[1];
  const int*   ea    = (const int*)d_in[2];
  const int*   batch = (const int*)d_in[3];
  const float* ae1   = (const float*)d_in[4];
  const float* ae2   = (const float*)d_in[5];
  const float* ee1   = (const float*)d_in[6];
  const float* ee2   = (const float*)d_in[7];
  const float* w1    = (const float*)d_in[8];
  const float* b1    = (const float*)d_in[9];
  const float* w2    = (const float*)d_in[10];
  const float* b2    = (const float*)d_in[11];
  const float* bng   = (const float*)d_in[12];
  const float* bnbp  = (const float*)d_in[13];
  const float* bnm   = (const float*)d_in[14];
  const float* bnv   = (const float*)d_in[15];
  const float* hw1   = (const float*)d_in[16];
  const float* hb1   = (const float*)d_in[17];
  const float* hw2   = (const float*)d_in[18];
  const float* hb2   = (const float*)d_in[19];
  float* out = (float*)d_out;

  char* ws = (char*)d_ws;
  size_t o = 0;
  auto alloc = [&](size_t bytes) { size_t p = o; o += (bytes + 255) & ~(size_t)255; return p; };
  __hip_bfloat16* h      = (__hip_bfloat16*)(ws + alloc((size_t)N_NODES * HPAD * 2));   // 60.8 MB
  __hip_bfloat16* aggb   = (__hip_bfloat16*)(ws + alloc((size_t)N_NODES * KP1 * 2));    // 64 MB
  __hip_bfloat16* w1b    = (__hip_bfloat16*)(ws + alloc((size_t)NLAYER * W1ROWS * KP1 * 2));
  __hip_bfloat16* w2b    = (__hip_bfloat16*)(ws + alloc((size_t)NLAYER * WID2 * W1ROWS * 2));
  __hip_bfloat16* hw1b   = (__hip_bfloat16*)(ws + alloc((size_t)512 * KP1 * 2));
  float*          comb   = (float*)         (ws + alloc((size_t)NLAYER * 10 * HPAD * 4));
  int*            offp   = (int*)           (ws + alloc((size_t)(N_NODES + 1) * 4));
  int*            cur    = (int*)           (ws + alloc((size_t)N_NODES * 4));
  int*            csr    = (int*)           (ws + alloc((size_t)N_EDGES * 4));
  __hip_bfloat16* pooled = (__hip_bfloat16*)(ws + alloc((size_t)N_GRAPH * KP1 * 2));
  int*            bsum   = (int*)           (ws + alloc(128 * 4));
  if (o > ws_size) {                        // ~136 MB total
    k_sentinel<<<1, 8, 0, stream>>>(out);   // absmax ~1e6 => ws_size too small
    return;
  }

  hipMemsetAsync(cur, 0, (size_t)N_NODES * 4, stream);

  // CSR by dst (deterministic structure; intra-node order via atomics, fp-order noise only)
  k_hist<<<(N_EDGES + 255) / 256, 256, 0, stream>>>(ei, cur);
  const int nsb = (N_NODES + 1023) / 1024;
  k_scan1<<<nsb, 1024, 0, stream>>>(cur, offp, bsum);
  k_scan2<<<1, 64, 0, stream>>>(bsum, nsb);
  k_scan3<<<(N_NODES + 255) / 256, 256, 0, stream>>>(offp, bsum);
  k_fill<<<(N_EDGES + 255) / 256, 256, 0, stream>>>(ei, ea, offp, cur, csr);

  k_wc1<<<(NLAYER * W1ROWS * KP1 + 255) / 256, 256, 0, stream>>>(w1, w1b);
  k_wc2<<<(NLAYER * WID2 * W1ROWS + 255) / 256, 256, 0, stream>>>(w2, w2b);
  k_wch<<<(512 * KP1 + 255) / 256, 256, 0, stream>>>(hw1, hw1b);
  k_comb<<<(NLAYER * 10 * HPAD + 255) / 256, 256, 0, stream>>>(ee1, ee2, comb);
  k_nemb<<<(N_NODES * 38 + 255) / 256, 256, 0, stream>>>(x, ae1, ae2, h);

  const int mlpBlocks = (N_NODES + MROWS - 1) / MROWS;   // 1563
  for (int l = 0; l < NLAYER; ++l) {
    k_agg<<<(N_NODES * 40 + 255) / 256, 256, 0, stream>>>(h, aggb, csr, offp,
        comb + l * 10 * HPAD);
    k_mlp<<<mlpBlocks, 256, 0, stream>>>(aggb,
        w1b + (size_t)l * W1ROWS * KP1, w2b + (size_t)l * WID2 * W1ROWS,
        b1 + l * 600, b2 + l * DIMD,
        bng + l * DIMD, bnbp + l * DIMD, bnm + l * DIMD, bnv + l * DIMD,
        (l < NLAYER - 1) ? 1 : 0, h);
  }

  k_pool<<<N_GRAPH, KP1, 0, stream>>>(h, batch, pooled);
  k_head<<<N_GRAPH / HGR, 256, 0, stream>>>(pooled, hw1b, hb1, hw2, hb2, out);
}